// Round 12
// baseline (149.210 us; speedup 1.0000x reference)
//
#include <hip/hip_runtime.h>
#include <hip/hip_bf16.h>

typedef __bf16 bf16x8 __attribute__((ext_vector_type(8)));
typedef __bf16 bf16x4 __attribute__((ext_vector_type(4)));
typedef float f32x4 __attribute__((ext_vector_type(4)));
typedef float f32x16 __attribute__((ext_vector_type(16)));
typedef unsigned int u32x4v __attribute__((ext_vector_type(4)));

#define D_ 128
#define T_ 2048
#define B_ 4
#define H_ 4
#define NB_ 2

// ===========================================================================
// Fragment-packed layouts (bf16, all frag loads are `base + lane*8`, 1KB):
//  wp[(j*NB+i)*32 + nt*4 + ks][lane][e]  = W[k=ks*32+(lane>>4)*8+e][n=nt*16+(lane&15)]
//  cp[(qrow>>4)*4 + h][lane][e]          = ctx A-frag pattern
//  qp[((b*64+qt)*4+h)*2+fs][lane][e]     = Q[b,qt*32+(lane&31)][h*32+fs*16+(lane>>5)*8+e]
//  kp[((b*4+h)*64+kt)*2+fs][lane][e]     = K[b,kt*32+(lane&31)][h*32+fs*16+(lane>>5)*8+e]
//  vp[((b*4+h)*64+tt)*2+fs][lane][e]     = V[b,tt*32+fs*16+(lane>>5)*8+e][h*32+(lane&31)]
// ===========================================================================

// ---------------------------------------------------------------------------
// Weight prep: fp32 [NB][128][128] -> frag-packed bf16 wp.
// ---------------------------------------------------------------------------
__global__ __launch_bounds__(256) void prep_weights(
    const float* __restrict__ Wq, const float* __restrict__ Wk,
    const float* __restrict__ Wv, const float* __restrict__ Wo,
    const float* __restrict__ W1, const float* __restrict__ W2,
    __bf16* __restrict__ wp)
{
  int tid = blockIdx.x * 256 + threadIdx.x;   // < 196608
  int e    = tid & 7;
  int lane = (tid >> 3) & 63;
  int ks   = (tid >> 9) & 3;
  int nt   = (tid >> 11) & 7;
  int i    = (tid >> 14) & (NB_ - 1);
  int j    = tid >> 15;
  int k = ks * 32 + (lane >> 4) * 8 + e;
  int n = nt * 16 + (lane & 15);
  const float* srcs[6] = {Wq, Wk, Wv, Wo, W1, W2};
  wp[tid] = (__bf16)srcs[j][i * 16384 + k * 128 + n];
}

// ---------------------------------------------------------------------------
// Fused posenc + LN + QKV (layer 0). 4 waves/block, wave w = head w.
// Loads fp32 inputs directly in A-frag pattern, adds PE inline, LN, QKV.
// ---------------------------------------------------------------------------
__global__ __launch_bounds__(256) void posln_qkv(
    const float* __restrict__ x, const __bf16* __restrict__ wpq,
    const __bf16* __restrict__ wpk, const __bf16* __restrict__ wpv,
    const float* __restrict__ bq, const float* __restrict__ bk,
    const float* __restrict__ bv, const float* __restrict__ g,
    const float* __restrict__ beta,
    __bf16* __restrict__ qp, __bf16* __restrict__ kp, __bf16* __restrict__ vp)
{
  int w = threadIdx.x >> 6, lane = threadIdx.x & 63;
  int m0 = blockIdx.x * 16;
  int lr = lane & 15, kg = lane >> 4;
  int row = m0 + lr;
  int t = row & (T_ - 1);

  // load fp32 A-frag elements + PE
  float araw[4][8];
  float s = 0.f, s2 = 0.f;
  #pragma unroll
  for (int ks = 0; ks < 4; ks++) {
    const float* xr = x + (size_t)row * D_ + ks * 32 + kg * 8;
    float4 x0 = *(const float4*)(xr);
    float4 x1 = *(const float4*)(xr + 4);
    const float* xv[2] = {&x0.x, &x1.x};
    #pragma unroll
    for (int e = 0; e < 8; e++) {
      int c = ks * 32 + kg * 8 + e;
      float arg = (float)t * exp2f(-0.20762050593045952f * (float)c);
      float pe = (c & 1) ? cosf(arg) : sinf(arg);
      float v = xv[e >> 2][e & 3] + pe;
      araw[ks][e] = v; s += v; s2 += v * v;
    }
  }
  s += __shfl_xor(s, 16, 64);  s2 += __shfl_xor(s2, 16, 64);
  s += __shfl_xor(s, 32, 64);  s2 += __shfl_xor(s2, 32, 64);
  float mu = s * (1.f / D_);
  float var = s2 * (1.f / D_) - mu * mu;
  float rstd = rsqrtf(var + 1e-3f);

  bf16x8 af[4];
  #pragma unroll
  for (int ks = 0; ks < 4; ks++) {
    int c0 = ks * 32 + kg * 8;
    float4 g0 = *(const float4*)(g + c0), g1 = *(const float4*)(g + c0 + 4);
    float4 q0 = *(const float4*)(beta + c0), q1 = *(const float4*)(beta + c0 + 4);
    const float* gp[2] = {&g0.x, &g1.x};
    const float* bp[2] = {&q0.x, &q1.x};
    #pragma unroll
    for (int e = 0; e < 8; e++)
      af[ks][e] = (__bf16)((araw[ks][e] - mu) * rstd * gp[e >> 2][e & 3] + bp[e >> 2][e & 3]);
  }

  #pragma unroll
  for (int i = 0; i < 2; i++) {
    int nt = w * 2 + i;
    const __bf16* wq = wpq + (size_t)(nt * 4) * 512 + lane * 8;
    const __bf16* wk = wpk + (size_t)(nt * 4) * 512 + lane * 8;
    const __bf16* wv = wpv + (size_t)(nt * 4) * 512 + lane * 8;
    f32x4 aq = {0, 0, 0, 0}, ak = {0, 0, 0, 0}, av = {0, 0, 0, 0};
    #pragma unroll
    for (int ks = 0; ks < 4; ks++) {
      aq = __builtin_amdgcn_mfma_f32_16x16x32_bf16(af[ks], *(const bf16x8*)(wq + ks * 512), aq, 0, 0, 0);
      ak = __builtin_amdgcn_mfma_f32_16x16x32_bf16(af[ks], *(const bf16x8*)(wk + ks * 512), ak, 0, 0, 0);
      av = __builtin_amdgcn_mfma_f32_16x16x32_bf16(af[ks], *(const bf16x8*)(wv + ks * 512), av, 0, 0, 0);
    }
    int col = nt * 16 + lr;
    float bqc = bq[col], bkc = bk[col], bvc = bv[col];
    int dk = i * 16 + lr;
    int hi8 = (lr >> 3) & 1;
    #pragma unroll
    for (int r = 0; r < 4; r++) {
      int rw = m0 + kg * 4 + r;
      int bb = rw >> 11, tt = rw & (T_ - 1);
      size_t qidx = ((((size_t)(bb * 64 + (tt >> 5)) * 4 + w) * 2 + i) * 512) +
                    ((tt & 31) + 32 * hi8) * 8 + (lr & 7);
      qp[qidx] = (__bf16)(aq[r] + bqc);
      size_t kidx = ((((size_t)(bb * 4 + w) * 64 + (tt >> 5)) * 2 + i) * 512) +
                    ((tt & 31) + 32 * hi8) * 8 + (lr & 7);
      kp[kidx] = (__bf16)(ak[r] + bkc);
      size_t vidx = ((((size_t)(bb * 4 + w) * 64 + (tt >> 5)) * 2 + ((tt >> 4) & 1)) * 512) +
                    (dk + 32 * ((tt >> 3) & 1)) * 8 + (tt & 7);
      vp[vidx] = (__bf16)(av[r] + bvc);
    }
  }
}

// ---------------------------------------------------------------------------
// Flash attention v9: 2 q-tiles per block sharing one K/V stream (halves KV
// L2 traffic, doubles MFMA per load). 8 waves x 8 iters (8-way KV split).
// Fixed-max softmax via C=-24, raw v_exp_f32, permlane32_swap. Frag-packed.
// XCD swizzle via bh = blk&15. Merge once via LDS (odd-stride, conflict-free).
// ---------------------------------------------------------------------------
__global__ __launch_bounds__(512) void attn9(
    const __bf16* __restrict__ qp, const __bf16* __restrict__ kp,
    const __bf16* __restrict__ vp, __bf16* __restrict__ cp)
{
  __shared__ float mbuf[7][64][35];   // [w-1][lane][accA16 accB16 lA lB]

  int w = threadIdx.x >> 6, lane = threadIdx.x & 63;
  int bh = blockIdx.x & 15, qtp = blockIdx.x >> 4;   // qtp 0..31
  int b = bh >> 2, h = bh & 3;
  int lq = lane & 31, hi = lane >> 5;
  int qtA = qtp * 2, qtB = qtp * 2 + 1;

  const float qscale = 0.17677669529663687f * 1.4426950408889634f;  // 1/sqrt(32)*log2e
  const __bf16* qbaseA = qp + (((size_t)(b * 64 + qtA) * 4 + h) * 2) * 512 + lane * 8;
  const __bf16* qbaseB = qp + (((size_t)(b * 64 + qtB) * 4 + h) * 2) * 512 + lane * 8;
  bf16x8 qA0, qA1, qB0, qB1;
  {
    bf16x8 ra0 = *(const bf16x8*)(qbaseA);
    bf16x8 ra1 = *(const bf16x8*)(qbaseA + 512);
    bf16x8 rb0 = *(const bf16x8*)(qbaseB);
    bf16x8 rb1 = *(const bf16x8*)(qbaseB + 512);
    #pragma unroll
    for (int e = 0; e < 8; e++) {
      qA0[e] = (__bf16)((float)ra0[e] * qscale);
      qA1[e] = (__bf16)((float)ra1[e] * qscale);
      qB0[e] = (__bf16)((float)rb0[e] * qscale);
      qB1[e] = (__bf16)((float)rb1[e] * qscale);
    }
  }

  const __bf16* kbase = kp + ((size_t)(b * 4 + h) * 64) * 1024 + lane * 8;
  const __bf16* vbase = vp + ((size_t)(b * 4 + h) * 64) * 1024 + lane * 8;

  f32x16 accA, accB;
  #pragma unroll
  for (int r = 0; r < 16; r++) { accA[r] = 0.f; accB[r] = 0.f; }
  float lA = 0.f, lB = 0.f;

  int kt = w * 8;
  bf16x8 kf0 = *(const bf16x8*)(kbase + (size_t)kt * 1024);
  bf16x8 kf1 = *(const bf16x8*)(kbase + (size_t)kt * 1024 + 512);
  bf16x8 vf0 = *(const bf16x8*)(vbase + (size_t)kt * 1024);
  bf16x8 vf1 = *(const bf16x8*)(vbase + (size_t)kt * 1024 + 512);

  for (int it = 0; it < 8; it++) {
    bf16x8 kn0, kn1, vn0, vn1;
    if (it < 7) {
      size_t nb = (size_t)(kt + 1) * 1024;
      kn0 = *(const bf16x8*)(kbase + nb);
      kn1 = *(const bf16x8*)(kbase + nb + 512);
      vn0 = *(const bf16x8*)(vbase + nb);
      vn1 = *(const bf16x8*)(vbase + nb + 512);
    }

    // ---- tile A: S, softmax, pack ----
    bf16x8 pwA0, pwA1;
    {
      __builtin_amdgcn_s_setprio(1);
      f32x16 s;
      #pragma unroll
      for (int r = 0; r < 16; r++) s[r] = -24.f;
      s = __builtin_amdgcn_mfma_f32_32x32x16_bf16(kf0, qA0, s, 0, 0, 0);
      s = __builtin_amdgcn_mfma_f32_32x32x16_bf16(kf1, qA1, s, 0, 0, 0);
      __builtin_amdgcn_s_setprio(0);
      unsigned int aw[8];
      #pragma unroll
      for (int g = 0; g < 4; g++) {
        float p0 = __builtin_amdgcn_exp2f(s[g * 4 + 0]);
        float p1 = __builtin_amdgcn_exp2f(s[g * 4 + 1]);
        float p2 = __builtin_amdgcn_exp2f(s[g * 4 + 2]);
        float p3 = __builtin_amdgcn_exp2f(s[g * 4 + 3]);
        lA += (p0 + p1) + (p2 + p3);
        unsigned int u01, u23;
        asm("v_cvt_pk_bf16_f32 %0, %1, %2" : "=v"(u01) : "v"(p0), "v"(p1));
        asm("v_cvt_pk_bf16_f32 %0, %1, %2" : "=v"(u23) : "v"(p2), "v"(p3));
        aw[g * 2] = u01; aw[g * 2 + 1] = u23;
      }
      unsigned int a0 = aw[0], a2 = aw[2];
      asm volatile("v_permlane32_swap_b32 %0, %1" : "+v"(a0), "+v"(a2));
      unsigned int a1 = aw[1], a3 = aw[3];
      asm volatile("v_permlane32_swap_b32 %0, %1" : "+v"(a1), "+v"(a3));
      pwA0 = __builtin_bit_cast(bf16x8, (u32x4v){a0, a1, a2, a3});
      unsigned int a4 = aw[4], a6 = aw[6];
      asm volatile("v_permlane32_swap_b32 %0, %1" : "+v"(a4), "+v"(a6));
      unsigned int a5 = aw[5], a7 = aw[7];
      asm volatile("v_permlane32_swap_b32 %0, %1" : "+v"(a5), "+v"(a7));
      pwA1 = __builtin_bit_cast(bf16x8, (u32x4v){a4, a5, a6, a7});
    }
    // ---- tile B: S, softmax, pack ----
    bf16x8 pwB0, pwB1;
    {
      __builtin_amdgcn_s_setprio(1);
      f32x16 s;
      #pragma unroll
      for (int r = 0; r < 16; r++) s[r] = -24.f;
      s = __builtin_amdgcn_mfma_f32_32x32x16_bf16(kf0, qB0, s, 0, 0, 0);
      s = __builtin_amdgcn_mfma_f32_32x32x16_bf16(kf1, qB1, s, 0, 0, 0);
      __builtin_amdgcn_s_setprio(0);
      unsigned int aw[8];
      #pragma unroll
      for (int g = 0; g < 4; g++) {
        float p0 = __builtin_amdgcn_exp2f(s[g * 4 + 0]);
        float p1 = __builtin_amdgcn_exp2f(s[g * 4 + 1]);
        float p2 = __builtin_amdgcn_exp2f(s[g * 4 + 2]);
        float p3 = __builtin_amdgcn_exp2f(s[g * 4 + 3]);
        lB += (p0 + p1) + (p2 + p3);
        unsigned int u01, u23;
        asm("v_cvt_pk_bf16_f32 %0, %1, %2" : "=v"(u01) : "v"(p0), "v"(p1));
        asm("v_cvt_pk_bf16_f32 %0, %1, %2" : "=v"(u23) : "v"(p2), "v"(p3));
        aw[g * 2] = u01; aw[g * 2 + 1] = u23;
      }
      unsigned int a0 = aw[0], a2 = aw[2];
      asm volatile("v_permlane32_swap_b32 %0, %1" : "+v"(a0), "+v"(a2));
      unsigned int a1 = aw[1], a3 = aw[3];
      asm volatile("v_permlane32_swap_b32 %0, %1" : "+v"(a1), "+v"(a3));
      pwB0 = __builtin_bit_cast(bf16x8, (u32x4v){a0, a1, a2, a3});
      unsigned int a4 = aw[4], a6 = aw[6];
      asm volatile("v_permlane32_swap_b32 %0, %1" : "+v"(a4), "+v"(a6));
      unsigned int a5 = aw[5], a7 = aw[7];
      asm volatile("v_permlane32_swap_b32 %0, %1" : "+v"(a5), "+v"(a7));
      pwB1 = __builtin_bit_cast(bf16x8, (u32x4v){a4, a5, a6, a7});
    }

    __builtin_amdgcn_s_setprio(1);
    accA = __builtin_amdgcn_mfma_f32_32x32x16_bf16(vf0, pwA0, accA, 0, 0, 0);
    accA = __builtin_amdgcn_mfma_f32_32x32x16_bf16(vf1, pwA1, accA, 0, 0, 0);
    accB = __builtin_amdgcn_mfma_f32_32x32x16_bf16(vf0, pwB0, accB, 0, 0, 0);
    accB = __builtin_amdgcn_mfma_f32_32x32x16_bf16(vf1, pwB1, accB, 0, 0, 0);
    __builtin_amdgcn_s_setprio(0);

    kf0 = kn0; kf1 = kn1; vf0 = vn0; vf1 = vn1;
    kt += 1;
  }

  lA += __shfl_xor(lA, 32, 64);
  lB += __shfl_xor(lB, 32, 64);

  if (w > 0) {
    float* mb = &mbuf[w - 1][lane][0];
    #pragma unroll
    for (int r = 0; r < 16; r++) { mb[r] = accA[r]; mb[16 + r] = accB[r]; }
    mb[32] = lA; mb[33] = lB;
  }
  __syncthreads();
  if (w == 0) {
    #pragma unroll
    for (int w2_ = 0; w2_ < 7; w2_++) {
      const float* mb = &mbuf[w2_][lane][0];
      #pragma unroll
      for (int r = 0; r < 16; r++) { accA[r] += mb[r]; accB[r] += mb[16 + r]; }
      lA += mb[32]; lB += mb[33];
    }
    float invA = 1.f / lA, invB = 1.f / lB;
    __bf16* cbA = cp + ((size_t)(b * 128 + qtA * 2 + (lq >> 4)) * 4 + h) * 512 + 4 * hi;
    __bf16* cbB = cp + ((size_t)(b * 128 + qtB * 2 + (lq >> 4)) * 4 + h) * 512 + 4 * hi;
    #pragma unroll
    for (int g = 0; g < 4; g++) {
      bf16x4 oA, oB;
      #pragma unroll
      for (int j = 0; j < 4; j++) {
        oA[j] = (__bf16)(accA[g * 4 + j] * invA);
        oB[j] = (__bf16)(accB[g * 4 + j] * invB);
      }
      *(bf16x4*)(cbA + ((lq & 15) + 16 * g) * 8) = oA;
      *(bf16x4*)(cbB + ((lq & 15) + 16 * g) * 8) = oB;
    }
  }
}

// ---------------------------------------------------------------------------
// Fused layer tail + next-layer QKV: Wo+bo -> LN -> W1+ReLU -> W2+res -> h,
// then LN(next) -> Q/K/V GEMMs -> packed stores.
// ---------------------------------------------------------------------------
__global__ __launch_bounds__(256) void wo_ffn_qkv(
    const __bf16* __restrict__ cp, const __bf16* __restrict__ wpo,
    const float* __restrict__ bo, const float* __restrict__ g1,
    const float* __restrict__ bt1, const __bf16* __restrict__ wp1,
    const float* __restrict__ b1, const __bf16* __restrict__ wp2,
    const float* __restrict__ b2,
    const float* __restrict__ gq, const float* __restrict__ btq,
    const __bf16* __restrict__ wpq, const __bf16* __restrict__ wpk,
    const __bf16* __restrict__ wpv,
    const float* __restrict__ bq, const float* __restrict__ bk,
    const float* __restrict__ bv,
    __bf16* __restrict__ qp, __bf16* __restrict__ kp, __bf16* __restrict__ vp)
{
  __shared__ __attribute__((aligned(16))) __bf16 tb0[16][128];
  __shared__ __attribute__((aligned(16))) __bf16 tb1[16][128];
  __shared__ float2 statb[16][4];

  int w = threadIdx.x >> 6, lane = threadIdx.x & 63;
  int m0 = blockIdx.x * 16;
  int lr = lane & 15, kg = lane >> 4;
  int swz = (lr & 7) << 3;

  bf16x8 af[4];
  #pragma unroll
  for (int ks = 0; ks < 4; ks++)
    af[ks] = *(const bf16x8*)(cp + ((size_t)blockIdx.x * 4 + ks) * 512 + lane * 8);

  f32x4 acc[2] = {{0, 0, 0, 0}, {0, 0, 0, 0}};
  #pragma unroll
  for (int i = 0; i < 2; i++) {
    const __bf16* wrow = wpo + (size_t)((w * 2 + i) * 4) * 512 + lane * 8;
    #pragma unroll
    for (int ks = 0; ks < 4; ks++)
      acc[i] = __builtin_amdgcn_mfma_f32_16x16x32_bf16(af[ks], *(const bf16x8*)(wrow + ks * 512), acc[i], 0, 0, 0);
  }

  float xv[2][4];
  float s[4] = {0, 0, 0, 0}, s2[4] = {0, 0, 0, 0};
  #pragma unroll
  for (int i = 0; i < 2; i++) {
    float bcol = bo[(w * 2 + i) * 16 + lr];
    #pragma unroll
    for (int r = 0; r < 4; r++) {
      float y = acc[i][r] + bcol;
      xv[i][r] = y; s[r] += y; s2[r] += y * y;
    }
  }
  #pragma unroll
  for (int r = 0; r < 4; r++)
    for (int mk = 1; mk < 16; mk <<= 1) {
      s[r] += __shfl_xor(s[r], mk, 64);
      s2[r] += __shfl_xor(s2[r], mk, 64);
    }
  if (lr == 0) {
    #pragma unroll
    for (int r = 0; r < 4; r++) statb[kg * 4 + r][w] = make_float2(s[r], s2[r]);
  }
  __syncthreads();
  float mu_[4], rstd_[4];
  #pragma unroll
  for (int r = 0; r < 4; r++) {
    int row = kg * 4 + r;
    float ss = 0.f, ss2 = 0.f;
    #pragma unroll
    for (int w2 = 0; w2 < 4; w2++) {
      float2 t = statb[row][w2];
      ss += t.x; ss2 += t.y;
    }
    mu_[r] = ss * (1.f / D_);
    float var = ss2 * (1.f / D_) - mu_[r] * mu_[r];
    rstd_[r] = rsqrtf(var + 1e-3f);
  }
  float hres[2][4];
  #pragma unroll
  for (int i = 0; i < 2; i++) {
    int col = (w * 2 + i) * 16 + lr;
    float gc = g1[col], bc = bt1[col];
    #pragma unroll
    for (int r = 0; r < 4; r++) {
      float y = (xv[i][r] - mu_[r]) * rstd_[r] * gc + bc;
      hres[i][r] = y;
      int row = kg * 4 + r;
      tb0[row][col ^ ((row & 7) << 3)] = (__bf16)y;
    }
  }
  __syncthreads();

  bf16x8 a2[4];
  #pragma unroll
  for (int ks = 0; ks < 4; ks++)
    a2[ks] = *(const bf16x8*)(&tb0[lr][(ks * 32 + kg * 8) ^ swz]);
  f32x4 acc2[2] = {{0, 0, 0, 0}, {0, 0, 0, 0}};
  #pragma unroll
  for (int i = 0; i < 2; i++) {
    const __bf16* wrow = wp1 + (size_t)((w * 2 + i) * 4) * 512 + lane * 8;
    #pragma unroll
    for (int ks = 0; ks < 4; ks++)
      acc2[i] = __builtin_amdgcn_mfma_f32_16x16x32_bf16(a2[ks], *(const bf16x8*)(wrow + ks * 512), acc2[i], 0, 0, 0);
  }
  #pragma unroll
  for (int i = 0; i < 2; i++) {
    float bcol = b1[(w * 2 + i) * 16 + lr];
    int col = (w * 2 + i) * 16 + lr;
    #pragma unroll
    for (int r = 0; r < 4; r++) {
      int row = kg * 4 + r;
      tb1[row][col ^ ((row & 7) << 3)] = (__bf16)fmaxf(acc2[i][r] + bcol, 0.f);
    }
  }
  __syncthreads();

  bf16x8 a3[4];
  #pragma unroll
  for (int ks = 0; ks < 4; ks++)
    a3[ks] = *(const bf16x8*)(&tb1[lr][(ks * 32 + kg * 8) ^ swz]);
  f32x4 acc3[2] = {{0, 0, 0, 0}, {0, 0, 0, 0}};
  #pragma unroll
  for (int i = 0; i < 2; i++) {
    const __bf16* wrow = wp2 + (size_t)((w * 2 + i) * 4) * 512 + lane * 8;
    #pragma unroll
    for (int ks = 0; ks < 4; ks++)
      acc3[i] = __builtin_amdgcn_mfma_f32_16x16x32_bf16(a3[ks], *(const bf16x8*)(wrow + ks * 512), acc3[i], 0, 0, 0);
  }

  // h -> tb0 transpose (safe: last tb0 read was a2)
  #pragma unroll
  for (int i = 0; i < 2; i++) {
    int col = (w * 2 + i) * 16 + lr;
    float bcol = b2[col];
    #pragma unroll
    for (int r = 0; r < 4; r++) {
      int row = kg * 4 + r;
      tb0[row][col ^ ((row & 7) << 3)] = (__bf16)(acc3[i][r] + bcol + hres[i][r]);
    }
  }
  __syncthreads();

  bf16x8 araw[4];
  #pragma unroll
  for (int ks = 0; ks < 4; ks++)
    araw[ks] = *(const bf16x8*)(&tb0[lr][(ks * 32 + kg * 8) ^ swz]);
  float t = 0.f, t2 = 0.f;
  #pragma unroll
  for (int ks = 0; ks < 4; ks++)
    #pragma unroll
    for (int e = 0; e < 8; e++) {
      float x = (float)araw[ks][e];
      t += x; t2 += x * x;
    }
  t += __shfl_xor(t, 16, 64);  t2 += __shfl_xor(t2, 16, 64);
  t += __shfl_xor(t, 32, 64);  t2 += __shfl_xor(t2, 32, 64);
  float mu = t * (1.f / D_);
  float var = t2 * (1.f / D_) - mu * mu;
  float rstd = rsqrtf(var + 1e-3f);

  bf16x8 af2[4];
  #pragma unroll
  for (int ks = 0; ks < 4; ks++) {
    int c0 = ks * 32 + kg * 8;
    float4 g0 = *(const float4*)(gq + c0), g1v = *(const float4*)(gq + c0 + 4);
    float4 q0 = *(const float4*)(btq + c0), q1 = *(const float4*)(btq + c0 + 4);
    const float* gp[2] = {&g0.x, &g1v.x};
    const float* bp[2] = {&q0.x, &q1.x};
    #pragma unroll
    for (int e = 0; e < 8; e++)
      af2[ks][e] = (__bf16)(((float)araw[ks][e] - mu) * rstd * gp[e >> 2][e & 3] + bp[e >> 2][e & 3]);
  }

  #pragma unroll
  for (int i = 0; i < 2; i++) {
    int nt = w * 2 + i;
    const __bf16* wq = wpq + (size_t)(nt * 4) * 512 + lane * 8;
    const __bf16* wk = wpk + (size_t)(nt * 4) * 512 + lane * 8;
    const __bf16* wv = wpv + (size_t)(nt * 4) * 512 + lane * 8;
    f32x4 aq = {0, 0, 0, 0}, ak = {0, 0, 0, 0}, av = {0, 0, 0, 0};
    #pragma unroll
    for (int ks = 0; ks < 4; ks++) {
      aq = __builtin_amdgcn_mfma_f32_16x16x32_bf16(af2[ks], *(const bf16x8*)(wq + ks * 512), aq, 0, 0, 0);
      ak = __builtin_amdgcn_mfma_f32_16x16x32_bf16(af2[ks], *(const bf16x8*)(wk + ks * 512), ak, 0, 0, 0);
      av = __builtin_amdgcn_mfma_f32_16x16x32_bf16(af2[ks], *(const bf16x8*)(wv + ks * 512), av, 0, 0, 0);
    }
    int col = nt * 16 + lr;
    float bqc = bq[col], bkc = bk[col], bvc = bv[col];
    int dk = i * 16 + lr;
    int hi8 = (lr >> 3) & 1;
    #pragma unroll
    for (int r = 0; r < 4; r++) {
      int row = m0 + kg * 4 + r;
      int bb = row >> 11, tt = row & (T_ - 1);
      size_t qidx = ((((size_t)(bb * 64 + (tt >> 5)) * 4 + w) * 2 + i) * 512) +
                    ((tt & 31) + 32 * hi8) * 8 + (lr & 7);
      qp[qidx] = (__bf16)(aq[r] + bqc);
      size_t kidx = ((((size_t)(bb * 4 + w) * 64 + (tt >> 5)) * 2 + i) * 512) +
                    ((tt & 31) + 32 * hi8) * 8 + (lr & 7);
      kp[kidx] = (__bf16)(ak[r] + bkc);
      size_t vidx = ((((size_t)(bb * 4 + w) * 64 + (tt >> 5)) * 2 + ((tt >> 4) & 1)) * 512) +
                    (dk + 32 * ((tt >> 3) & 1)) * 8 + (tt & 7);
      vp[vidx] = (__bf16)(av[r] + bvc);
    }
  }
}

// ---------------------------------------------------------------------------
// Final layer tail: Wo+bo -> LN -> W1+ReLU -> W2+res -> final LN -> fp32 out.
// ---------------------------------------------------------------------------
__global__ __launch_bounds__(256) void wo_ffn_last(
    const __bf16* __restrict__ cp, const __bf16* __restrict__ wpo,
    const float* __restrict__ bo, const float* __restrict__ g1,
    const float* __restrict__ bt1, const __bf16* __restrict__ wp1,
    const float* __restrict__ b1, const __bf16* __restrict__ wp2,
    const float* __restrict__ b2, const float* __restrict__ g2,
    const float* __restrict__ bt2, float* __restrict__ outf)
{
  __shared__ __attribute__((aligned(16))) __bf16 tb0[16][128];
  __shared__ __attribute__((aligned(16))) __bf16 tb1[16][128];
  __shared__ float2 statb[16][4];

  int w = threadIdx.x >> 6, lane = threadIdx.x & 63;
  int m0 = blockIdx.x * 16;
  int lr = lane & 15, kg = lane >> 4;
  int swz = (lr & 7) << 3;

  bf16x8 af[4];
  #pragma unroll
  for (int ks = 0; ks < 4; ks++)
    af[ks] = *(const bf16x8*)(cp + ((size_t)blockIdx.x * 4 + ks) * 512 + lane * 8);

  f32x4 acc[2] = {{0, 0, 0, 0}, {0, 0, 0, 0}};
  #pragma unroll
  for (int i = 0; i < 2; i++) {
    const __bf16* wrow = wpo + (size_t)((w * 2 + i) * 4) * 512 + lane * 8;
    #pragma unroll
    for (int ks = 0; ks < 4; ks++)
      acc[i] = __builtin_amdgcn_mfma_f32_16x16x32_bf16(af[ks], *(const bf16x8*)(wrow + ks * 512), acc[i], 0, 0, 0);
  }

  float xv[2][4];
  float s[4] = {0, 0, 0, 0}, s2[4] = {0, 0, 0, 0};
  #pragma unroll
  for (int i = 0; i < 2; i++) {
    float bcol = bo[(w * 2 + i) * 16 + lr];
    #pragma unroll
    for (int r = 0; r < 4; r++) {
      float y = acc[i][r] + bcol;
      xv[i][r] = y; s[r] += y; s2[r] += y * y;
    }
  }
  #pragma unroll
  for (int r = 0; r < 4; r++)
    for (int mk = 1; mk < 16; mk <<= 1) {
      s[r] += __shfl_xor(s[r], mk, 64);
      s2[r] += __shfl_xor(s2[r], mk, 64);
    }
  if (lr == 0) {
    #pragma unroll
    for (int r = 0; r < 4; r++) statb[kg * 4 + r][w] = make_float2(s[r], s2[r]);
  }
  __syncthreads();
  float mu_[4], rstd_[4];
  #pragma unroll
  for (int r = 0; r < 4; r++) {
    int row = kg * 4 + r;
    float ss = 0.f, ss2 = 0.f;
    #pragma unroll
    for (int w2 = 0; w2 < 4; w2++) {
      float2 t = statb[row][w2];
      ss += t.x; ss2 += t.y;
    }
    mu_[r] = ss * (1.f / D_);
    float var = ss2 * (1.f / D_) - mu_[r] * mu_[r];
    rstd_[r] = rsqrtf(var + 1e-3f);
  }
  float hres[2][4];
  #pragma unroll
  for (int i = 0; i < 2; i++) {
    int col = (w * 2 + i) * 16 + lr;
    float gc = g1[col], bc = bt1[col];
    #pragma unroll
    for (int r = 0; r < 4; r++) {
      float y = (xv[i][r] - mu_[r]) * rstd_[r] * gc + bc;
      hres[i][r] = y;
      int row = kg * 4 + r;
      tb0[row][col ^ ((row & 7) << 3)] = (__bf16)y;
    }
  }
  __syncthreads();

  bf16x8 a2[4];
  #pragma unroll
  for (int ks = 0; ks < 4; ks++)
    a2[ks] = *(const bf16x8*)(&tb0[lr][(ks * 32 + kg * 8) ^ swz]);
  f32x4 acc2[2] = {{0, 0, 0, 0}, {0, 0, 0, 0}};
  #pragma unroll
  for (int i = 0; i < 2; i++) {
    const __bf16* wrow = wp1 + (size_t)((w * 2 + i) * 4) * 512 + lane * 8;
    #pragma unroll
    for (int ks = 0; ks < 4; ks++)
      acc2[i] = __builtin_amdgcn_mfma_f32_16x16x32_bf16(a2[ks], *(const bf16x8*)(wrow + ks * 512), acc2[i], 0, 0, 0);
  }
  #pragma unroll
  for (int i = 0; i < 2; i++) {
    float bcol = b1[(w * 2 + i) * 16 + lr];
    int col = (w * 2 + i) * 16 + lr;
    #pragma unroll
    for (int r = 0; r < 4; r++) {
      int row = kg * 4 + r;
      tb1[row][col ^ ((row & 7) << 3)] = (__bf16)fmaxf(acc2[i][r] + bcol, 0.f);
    }
  }
  __syncthreads();

  bf16x8 a3[4];
  #pragma unroll
  for (int ks = 0; ks < 4; ks++)
    a3[ks] = *(const bf16x8*)(&tb1[lr][(ks * 32 + kg * 8) ^ swz]);
  f32x4 acc3[2] = {{0, 0, 0, 0}, {0, 0, 0, 0}};
  #pragma unroll
  for (int i = 0; i < 2; i++) {
    const __bf16* wrow = wp2 + (size_t)((w * 2 + i) * 4) * 512 + lane * 8;
    #pragma unroll
    for (int ks = 0; ks < 4; ks++)
      acc3[i] = __builtin_amdgcn_mfma_f32_16x16x32_bf16(a3[ks], *(const bf16x8*)(wrow + ks * 512), acc3[i], 0, 0, 0);
  }

  float yv[2][4];
  float t[4] = {0, 0, 0, 0}, t2[4] = {0, 0, 0, 0};
  #pragma unroll
  for (int i = 0; i < 2; i++) {
    float bcol = b2[(w * 2 + i) * 16 + lr];
    #pragma unroll
    for (int r = 0; r < 4; r++) {
      float y = acc3[i][r] + bcol + hres[i][r];
      yv[i][r] = y; t[r] += y; t2[r] += y * y;
    }
  }
  #pragma unroll
  for (int r = 0; r < 4; r++)
    for (int mk = 1; mk < 16; mk <<= 1) {
      t[r] += __shfl_xor(t[r], mk, 64);
      t2[r] += __shfl_xor(t2[r], mk, 64);
    }
  __syncthreads();
  if (lr == 0) {
    #pragma unroll
    for (int r = 0; r < 4; r++) statb[kg * 4 + r][w] = make_float2(t[r], t2[r]);
  }
  __syncthreads();
  #pragma unroll
  for (int r = 0; r < 4; r++) {
    int row = kg * 4 + r;
    float ss = 0.f, ss2 = 0.f;
    #pragma unroll
    for (int w2 = 0; w2 < 4; w2++) {
      float2 tt = statb[row][w2];
      ss += tt.x; ss2 += tt.y;
    }
    float mu = ss * (1.f / D_);
    float var = ss2 * (1.f / D_) - mu * mu;
    float rstd = rsqrtf(var + 1e-3f);
    #pragma unroll
    for (int i = 0; i < 2; i++) {
      int col = (w * 2 + i) * 16 + lr;
      outf[(size_t)(m0 + row) * D_ + col] =
          (yv[i][r] - mu) * rstd * g2[col] + bt2[col];
    }
  }
}

// ---------------------------------------------------------------------------
extern "C" void kernel_launch(void* const* d_in, const int* in_sizes, int n_in,
                              void* d_out, int out_size, void* d_ws, size_t ws_size,
                              hipStream_t stream)
{
  const float* inputs = (const float*)d_in[0];
  const float* Wq = (const float*)d_in[1];
  const float* bq = (const float*)d_in[2];
  const float* Wk = (const float*)d_in[3];
  const float* bk = (const float*)d_in[4];
  const float* Wv = (const float*)d_in[5];
  const float* bv = (const float*)d_in[6];
  const float* Wo = (const float*)d_in[7];
  const float* bo = (const float*)d_in[8];
  const float* W1 = (const float*)d_in[9];
  const float* b1 = (const float*)d_in[10];
  const float* W2 = (const float*)d_in[11];
  const float* b2 = (const float*)d_in[12];
  const float* ln_g = (const float*)d_in[13];
  const float* ln_b = (const float*)d_in[14];
  float* out = (float*)d_out;

  char* ws = (char*)d_ws;
  size_t off = 0;
  auto alloc = [&](size_t bytes) {
    void* p = ws + off;
    off = (off + bytes + 255) & ~(size_t)255;
    return p;
  };
  const size_t ACT = (size_t)8192 * 128 * sizeof(__bf16);  // 2 MB
  __bf16* wp = (__bf16*)alloc((size_t)6 * NB_ * 16384 * sizeof(__bf16));
  __bf16* qp = (__bf16*)alloc(ACT);
  __bf16* kp = (__bf16*)alloc(ACT);
  __bf16* vp = (__bf16*)alloc(ACT);
  __bf16* cb = (__bf16*)alloc(ACT);

  prep_weights<<<768, 256, 0, stream>>>(Wq, Wk, Wv, Wo, W1, W2, wp);

  const __bf16* wpq0 = wp + (size_t)(0 * NB_ + 0) * 16384;
  const __bf16* wpk0 = wp + (size_t)(1 * NB_ + 0) * 16384;
  const __bf16* wpv0 = wp + (size_t)(2 * NB_ + 0) * 16384;
  const __bf16* wpo0 = wp + (size_t)(3 * NB_ + 0) * 16384;
  const __bf16* wp10 = wp + (size_t)(4 * NB_ + 0) * 16384;
  const __bf16* wp20 = wp + (size_t)(5 * NB_ + 0) * 16384;
  const __bf16* wpq1 = wp + (size_t)(0 * NB_ + 1) * 16384;
  const __bf16* wpk1 = wp + (size_t)(1 * NB_ + 1) * 16384;
  const __bf16* wpv1 = wp + (size_t)(2 * NB_ + 1) * 16384;
  const __bf16* wpo1 = wp + (size_t)(3 * NB_ + 1) * 16384;
  const __bf16* wp11 = wp + (size_t)(4 * NB_ + 1) * 16384;
  const __bf16* wp21 = wp + (size_t)(5 * NB_ + 1) * 16384;

  // layer 0 (posenc + LN + QKV fused)
  posln_qkv<<<512, 256, 0, stream>>>(inputs, wpq0, wpk0, wpv0, bq, bk, bv,
                                     ln_g, ln_b, qp, kp, vp);
  attn9<<<512, 512, 0, stream>>>(qp, kp, vp, cb);
  wo_ffn_qkv<<<512, 256, 0, stream>>>(cb, wpo0, bo,
                                      ln_g + 128, ln_b + 128, wp10, b1, wp20, b2,
                                      ln_g + 2 * 128, ln_b + 2 * 128,
                                      wpq1, wpk1, wpv1,
                                      bq + 128, bk + 128, bv + 128,
                                      qp, kp, vp);
  // layer 1
  attn9<<<512, 512, 0, stream>>>(qp, kp, vp, cb);
  wo_ffn_last<<<512, 256, 0, stream>>>(cb, wpo1, bo + 128,
                                       ln_g + 3 * 128, ln_b + 3 * 128,
                                       wp11, b1 + 128, wp21, b2 + 128,
                                       ln_g + 3 * 128, ln_b + 3 * 128, out);
}